// Round 1
// baseline (8721.246 us; speedup 1.0000x reference)
//
#include <hip/hip_runtime.h>

typedef unsigned int u32;
typedef _Float16 half2v __attribute__((ext_vector_type(2)));

#define T_LEN 2048
#define NEG (-10000.0f)

// ---------- helpers ----------
__device__ __forceinline__ float fdot2u(u32 w, u32 h, float acc) {
#if __has_builtin(__builtin_amdgcn_fdot2)
  return __builtin_amdgcn_fdot2(__builtin_bit_cast(half2v, w),
                                __builtin_bit_cast(half2v, h), acc, false);
#else
  half2v a = __builtin_bit_cast(half2v, w);
  half2v b = __builtin_bit_cast(half2v, h);
  return acc + (float)a[0] * (float)b[0] + (float)a[1] * (float)b[1];
#endif
}

__device__ __forceinline__ u32 pack2(float lo, float hi) {
  _Float16 l = (_Float16)lo;  // RN
  _Float16 h = (_Float16)hi;
  unsigned short ul = __builtin_bit_cast(unsigned short, l);
  unsigned short uh = __builtin_bit_cast(unsigned short, h);
  return ((u32)uh << 16) | (u32)ul;
}

// ---------- kernel 1: pack Whh (both dirs) into fp16-pair layout ----------
// reg region : m in [0,92)   at (d*92+m)*1024 + g        (col-major for coalesced preload)
// lds region : r=m-92 in [0,36) at 188416 + (d*36+r)*1024 + g
__global__ void pack_whh(const float* __restrict__ Wf, const float* __restrict__ Wb,
                         u32* __restrict__ WP) {
  int idx = blockIdx.x * 256 + threadIdx.x;   // < 262144
  int d   = idx >> 17;
  int rem = idx & 131071;
  int m   = rem >> 10;
  int g   = rem & 1023;
  const float* W = d ? Wb : Wf;
  float2 v = ((const float2*)(W + g * 256))[m];
  u32 p = pack2(v.x, v.y);
  int dest = (m < 92) ? ((d * 92 + m) * 1024 + g)
                      : (188416 + (d * 36 + (m - 92)) * 1024 + g);
  WP[dest] = p;
}

// ---------- kernel 2: embedding gather ----------
__global__ void gather_kernel(const int* __restrict__ words,
                              const float* __restrict__ embed,
                              float* __restrict__ xs) {
  int t = blockIdx.x;
  int k = threadIdx.x;
  xs[t * 256 + k] = embed[(size_t)words[t] * 256 + k];
}

// ---------- kernel 3: XW[d][t][g] = xs[t]·Wih_d[g] + bih[g] + bhh[g] ----------
__global__ __launch_bounds__(256) void gemm_xw(
    const float* __restrict__ xs,
    const float* __restrict__ Wf, const float* __restrict__ Wb,
    const float* __restrict__ bihf, const float* __restrict__ bhhf,
    const float* __restrict__ bihb, const float* __restrict__ bhhb,
    float* __restrict__ XW) {
  __shared__ float lx[32 * 256];
  __shared__ float lw[32 * 132];
  const int tid = threadIdx.x;
  const int t0 = blockIdx.x * 32;
  const int g0 = blockIdx.y * 128;
  const int d  = blockIdx.z;
  const float* W = d ? Wb : Wf;

  #pragma unroll 4
  for (int r = 0; r < 32; ++r) lx[r * 256 + tid] = xs[(t0 + r) * 256 + tid];

  const int tg = tid & 31, tt = tid >> 5;
  float acc[4][4] = {};

  for (int kc = 0; kc < 8; ++kc) {
    __syncthreads();
    #pragma unroll
    for (int r2 = 0; r2 < 16; ++r2) {
      int gg = r2 * 8 + (tid >> 5);
      int k  = tid & 31;
      lw[k * 132 + gg] = W[(g0 + gg) * 256 + kc * 32 + k];
    }
    __syncthreads();
    #pragma unroll
    for (int k = 0; k < 32; ++k) {
      float4 wv = *(const float4*)&lw[k * 132 + tg * 4];
      #pragma unroll
      for (int a = 0; a < 4; ++a) {
        float xa = lx[(tt * 4 + a) * 256 + kc * 32 + k];
        acc[a][0] = fmaf(xa, wv.x, acc[a][0]);
        acc[a][1] = fmaf(xa, wv.y, acc[a][1]);
        acc[a][2] = fmaf(xa, wv.z, acc[a][2]);
        acc[a][3] = fmaf(xa, wv.w, acc[a][3]);
      }
    }
  }
  const float* bih = d ? bihb : bihf;
  const float* bhh = d ? bhhb : bhhf;
  int gcol = g0 + tg * 4;
  float4 bb;
  bb.x = bih[gcol + 0] + bhh[gcol + 0];
  bb.y = bih[gcol + 1] + bhh[gcol + 1];
  bb.z = bih[gcol + 2] + bhh[gcol + 2];
  bb.w = bih[gcol + 3] + bhh[gcol + 3];
  #pragma unroll
  for (int a = 0; a < 4; ++a) {
    float4 o;
    o.x = acc[a][0] + bb.x;
    o.y = acc[a][1] + bb.y;
    o.z = acc[a][2] + bb.z;
    o.w = acc[a][3] + bb.w;
    *(float4*)&XW[((size_t)d * T_LEN + t0 + tt * 4 + a) * 1024 + gcol] = o;
  }
}

// ---------- kernel 4: the sequential bidirectional LSTM ----------
// grid = 2 (d = direction), block = 1024 (thread g = gate row), dyn LDS 152064 B
// LDS dwords: [0,36864) W-lds (18 b64-pairs * 2048), [36864,36992) H2 packed h,
//             [36992,38016) gates fp32
__global__ __launch_bounds__(1024, 4) void lstm_seq(
    const float* __restrict__ XW, float* __restrict__ HS,
    const u32* __restrict__ wpack,
    const float* __restrict__ h0, const float* __restrict__ c0) {
  extern __shared__ u32 smem[];
  const int g = threadIdx.x;
  const int d = blockIdx.x;

  u32 w[92];
  #pragma unroll
  for (int m = 0; m < 92; ++m) w[m] = wpack[(d * 92 + m) * 1024 + g];
  #pragma unroll
  for (int r = 0; r < 36; ++r)
    smem[(r >> 1) * 2048 + (g << 1) + (r & 1)] = wpack[188416 + (d * 36 + r) * 1024 + g];

  u32*   H2 = smem + 36864;
  float* GT = (float*)(smem + 36992);

  float c = 0.0f, h = 0.0f;
  if (g < 256) {
    c = c0[d * 256 + g];
    h = h0[d * 256 + g];
    float hp = __shfl_xor(h, 1);
    if (!(g & 1)) H2[g >> 1] = pack2(h, hp);
  }
  __syncthreads();

  const int delta = d ? -1024 : 1024;
  const float* xwp = XW + ((size_t)d * T_LEN + (d ? (T_LEN - 1) : 0)) * 1024 + g;
  float xw_cur = *xwp;

  for (int s = 0; s < T_LEN; ++s) {
    float xw_next = 0.0f;
    if (s < T_LEN - 1) { xwp += delta; xw_next = *xwp; }

    float acc = xw_cur;
    const uint4* H2v = (const uint4*)H2;
    #pragma unroll
    for (int b = 0; b < 23; ++b) {            // h dwords [0,92) from registers
      uint4 hv = H2v[b];
      acc = fdot2u(w[4 * b + 0], hv.x, acc);
      acc = fdot2u(w[4 * b + 1], hv.y, acc);
      acc = fdot2u(w[4 * b + 2], hv.z, acc);
      acc = fdot2u(w[4 * b + 3], hv.w, acc);
    }
    #pragma unroll
    for (int qq = 0; qq < 9; ++qq) {          // h dwords [92,128) from LDS W
      uint4 hv = H2v[23 + qq];
      uint2 w0 = *(const uint2*)&smem[(2 * qq) * 2048 + (g << 1)];
      uint2 w1 = *(const uint2*)&smem[(2 * qq + 1) * 2048 + (g << 1)];
      acc = fdot2u(w0.x, hv.x, acc);
      acc = fdot2u(w0.y, hv.y, acc);
      acc = fdot2u(w1.x, hv.z, acc);
      acc = fdot2u(w1.y, hv.w, acc);
    }
    GT[g] = acc;
    __syncthreads();

    const int t = d ? (T_LEN - 1 - s) : s;
    if (g < 256) {
      float gi = GT[g];
      float gf = GT[256 + g];
      float gc = GT[512 + g];
      float go = GT[768 + g];
      gi = 1.0f / (1.0f + __expf(-gi));
      gf = 1.0f / (1.0f + __expf(-gf));
      go = 1.0f / (1.0f + __expf(-go));
      gc = 1.0f - 2.0f / (__expf(2.0f * gc) + 1.0f);   // tanh
      c = gf * c + gi * gc;
      float th = 1.0f - 2.0f / (__expf(2.0f * c) + 1.0f);
      h = go * th;
      HS[((size_t)d * T_LEN + t) * 256 + g] = h;
      float hp = __shfl_xor(h, 1);
      if (!(g & 1)) H2[g >> 1] = pack2(h, hp);
    }
    __syncthreads();
    xw_cur = xw_next;
  }
}

// ---------- kernel 5: feats[t][n] = [hs_f ; hs_b]·W_out[n] + b_out[n] ----------
// grid 128 blocks * 128 threads, 16 t per block
__global__ void feats_kernel(const float* __restrict__ hs,
                             const float* __restrict__ wout,
                             const float* __restrict__ bout,
                             float* __restrict__ feats) {
  __shared__ float lf[16 * 257];
  __shared__ float lb[16 * 257];
  const int tid = threadIdx.x;   // 128
  const int t0 = blockIdx.x * 16;
  for (int i = tid; i < 16 * 256; i += 128) {
    int r = i >> 8, k = i & 255;
    lf[r * 257 + k] = hs[(size_t)(t0 + r) * 256 + k];
    lb[r * 257 + k] = hs[(size_t)T_LEN * 256 + (size_t)(t0 + r) * 256 + k];
  }
  __syncthreads();
  const int tl = tid >> 3, n = tid & 7;
  if (n < 7) {
    float acc = bout[n];
    #pragma unroll 8
    for (int k = 0; k < 256; ++k) acc = fmaf(lf[tl * 257 + k], wout[n * 512 + k], acc);
    #pragma unroll 8
    for (int k = 0; k < 256; ++k) acc = fmaf(lb[tl * 257 + k], wout[n * 512 + 256 + k], acc);
    feats[(t0 + tl) * 7 + n] = acc;
  }
}

// ---------- kernel 6: Viterbi decode (1 wave) ----------
__global__ void viterbi_kernel(const float* __restrict__ feats,
                               const float* __restrict__ trans,
                               float* __restrict__ out) {
  __shared__ unsigned char bp[T_LEN][8];
  const int j  = threadIdx.x;          // 64 threads = 1 wave
  const int jc = (j < 7) ? j : 0;
  float Trow[7];
  #pragma unroll
  for (int i = 0; i < 7; ++i) Trow[i] = trans[jc * 7 + i];
  float fv = (j == 5) ? 0.0f : NEG;    // START = 5
  float fcur = feats[jc];
  for (int t = 0; t < T_LEN; ++t) {
    float fnext = (t < T_LEN - 1) ? feats[(t + 1) * 7 + jc] : 0.0f;
    float f0 = __shfl(fv, 0), f1 = __shfl(fv, 1), f2 = __shfl(fv, 2),
          f3 = __shfl(fv, 3), f4 = __shfl(fv, 4), f5 = __shfl(fv, 5),
          f6 = __shfl(fv, 6);
    float best = f0 + Trow[0]; int bi = 0;
    float v;
    v = f1 + Trow[1]; if (v > best) { best = v; bi = 1; }
    v = f2 + Trow[2]; if (v > best) { best = v; bi = 2; }
    v = f3 + Trow[3]; if (v > best) { best = v; bi = 3; }
    v = f4 + Trow[4]; if (v > best) { best = v; bi = 4; }
    v = f5 + Trow[5]; if (v > best) { best = v; bi = 5; }
    v = f6 + Trow[6]; if (v > best) { best = v; bi = 6; }
    if (j < 7) {
      bp[t][j] = (unsigned char)bi;
      fv = best + fcur;
    }
    fcur = fnext;
  }
  float term = fv + trans[42 + jc];    // transitions[END=6][j]
  float best = __shfl(term, 0); int bt = 0;
  #pragma unroll
  for (int i = 1; i < 7; ++i) {
    float ti = __shfl(term, i);
    if (ti > best) { best = ti; bt = i; }
  }
  __syncthreads();
  if (j == 0) {
    out[0] = best;
    int tag = bt;
    for (int t = T_LEN - 1; t >= 0; --t) {
      out[1 + t] = (float)tag;
      tag = bp[t][tag];
    }
  }
}

// ---------- host ----------
extern "C" void kernel_launch(void* const* d_in, const int* in_sizes, int n_in,
                              void* d_out, int out_size, void* d_ws, size_t ws_size,
                              hipStream_t stream) {
  const int*   words = (const int*)d_in[0];
  const float* embed = (const float*)d_in[1];
  const float* Wih_f = (const float*)d_in[2];
  const float* Whh_f = (const float*)d_in[3];
  const float* bih_f = (const float*)d_in[4];
  const float* bhh_f = (const float*)d_in[5];
  const float* Wih_b = (const float*)d_in[6];
  const float* Whh_b = (const float*)d_in[7];
  const float* bih_b = (const float*)d_in[8];
  const float* bhh_b = (const float*)d_in[9];
  const float* Wout  = (const float*)d_in[10];
  const float* bout  = (const float*)d_in[11];
  const float* trans = (const float*)d_in[12];
  const float* h0    = (const float*)d_in[13];
  const float* c0    = (const float*)d_in[14];

  float* ws = (float*)d_ws;
  float* XW = ws;                        // 2*2048*1024           = 4,194,304 f
  float* HS = ws + 4194304;              // 2*2048*256            = 1,048,576 f
  float* XS = ws + 5242880;              // 2048*256              =   524,288 f
  float* FE = ws + 5767168;              // 2048*7                =    14,336 f
  u32*   WP = (u32*)(ws + 5781504);      // 262,144 dwords

  pack_whh<<<1024, 256, 0, stream>>>(Whh_f, Whh_b, WP);
  gather_kernel<<<T_LEN, 256, 0, stream>>>(words, embed, XS);
  dim3 ggrid(T_LEN / 32, 1024 / 128, 2);
  gemm_xw<<<ggrid, 256, 0, stream>>>(XS, Wih_f, Wih_b, bih_f, bhh_f, bih_b, bhh_b, XW);
  lstm_seq<<<2, 1024, 152064, stream>>>(XW, HS, WP, h0, c0);
  feats_kernel<<<128, 128, 0, stream>>>(HS, Wout, bout, FE);
  viterbi_kernel<<<1, 64, 0, stream>>>(FE, trans, (float*)d_out);
}